// Round 1
// baseline (630.384 us; speedup 1.0000x reference)
//
#include <hip/hip_runtime.h>
#include <hip/hip_bf16.h>
#include <stdint.h>

// Swin window-attention, MI355X. bf16 MFMA pipeline:
//  gather_cvt_x -> cvt_w -> gemm_bt<0> (QKV) -> attn -> gemm_bt<1> (proj+scatter)

typedef __bf16 v8bf __attribute__((ext_vector_type(8)));
typedef __bf16 v4bf __attribute__((ext_vector_type(4)));
typedef float  v4f  __attribute__((ext_vector_type(4)));

#define MFMA16(a,b,c) __builtin_amdgcn_mfma_f32_16x16x32_bf16(a,b,c,0,0,0)

typedef const void __attribute__((address_space(1))) gas_t;
typedef void __attribute__((address_space(3))) las_t;

__device__ __forceinline__ void gl2lds16(const void* g, void* l) {
  __builtin_amdgcn_global_load_lds((gas_t*)g, (las_t*)l, 16, 0, 0);
}

// ---------------- gather (roll -3,-3 + window partition) + f32->bf16 ----------------
// x [32][56][56][384] f32  ->  Xw [100352][384] bf16, row m = win*49+tok
__global__ __launch_bounds__(256) void gather_cvt_x(const float* __restrict__ x,
                                                    __bf16* __restrict__ xw) {
  uint32_t cid = blockIdx.x * 256u + threadIdx.x;          // < 100352*96
  uint32_t m   = cid / 96u, c4 = cid - (cid / 96u) * 96u;
  uint32_t win = m / 49u,  tok = m - win * 49u;
  uint32_t b  = win >> 6,  wy = (win >> 3) & 7u, wx = win & 7u;
  uint32_t ty = tok / 7u,  tx = tok - ty * 7u;
  uint32_t sy = wy * 7u + ty + 3u; if (sy >= 56u) sy -= 56u;
  uint32_t sx = wx * 7u + tx + 3u; if (sx >= 56u) sx -= 56u;
  const float4 v = *(const float4*)(x + (((size_t)(b * 56u + sy)) * 56u + sx) * 384u + c4 * 4u);
  v4bf o; o[0] = (__bf16)v.x; o[1] = (__bf16)v.y; o[2] = (__bf16)v.z; o[3] = (__bf16)v.w;
  *(v4bf*)(xw + (size_t)m * 384u + c4 * 4u) = o;
}

// ---------------- weight conversion f32->bf16 ----------------
__global__ __launch_bounds__(256) void cvt_w_kernel(const float* __restrict__ qw,
                                                    const float* __restrict__ pw,
                                                    __bf16* __restrict__ dq,
                                                    __bf16* __restrict__ dp) {
  uint32_t cid = blockIdx.x * 256u + threadIdx.x;          // < 147456
  uint32_t e = cid * 4u;
  const float* src; __bf16* dst; uint32_t off;
  if (e < 442368u) { src = qw; dst = dq; off = e; }
  else             { src = pw; dst = dp; off = e - 442368u; }
  float4 v = *(const float4*)(src + off);
  v4bf o; o[0] = (__bf16)v.x; o[1] = (__bf16)v.y; o[2] = (__bf16)v.z; o[3] = (__bf16)v.w;
  *(v4bf*)(dst + off) = o;
}

// ---------------- BT GEMM: C[m,n] = sum_k A[m,k]*B[n,k] (+bias), K=384 ----------------
// 128x128 tile, BK=32, 4 waves, m97 structure (global_load_lds width 16).
// EPI 0: QKV epilogue -> Q/K/V [win][head][tok][32] bf16 (q pre-scaled)
// EPI 1: proj epilogue -> window-reverse + roll(+3,+3) scatter, f32 out
template<int EPI>
__global__ __launch_bounds__(256) void gemm_bt(const __bf16* __restrict__ A,
                                               const __bf16* __restrict__ B,
                                               const float* __restrict__ biasv,
                                               __bf16* __restrict__ Qp,
                                               __bf16* __restrict__ Kp,
                                               __bf16* __restrict__ Vp,
                                               float* __restrict__ Op) {
  __shared__ __bf16 lds_a[128 * 32];
  __shared__ __bf16 lds_b[128 * 32];
  const int tid = threadIdx.x, wv = tid >> 6, ln = tid & 63;
  const int wr = wv >> 1, wc = wv & 1;
  const int c = ln & 15, rq = (ln >> 4) * 4;
  const uint32_t m0 = blockIdx.y * 128u, n0 = blockIdx.x * 128u;
  v4f acc[4][4] = {};
  for (int ks = 0; ks < 12; ++ks) {
    const uint32_t k0 = ks * 32u;
    // stage 8KB A + 8KB B: 8 chunks of 1KB each, 2 chunks per wave per matrix
    for (int ch = wv; ch < 8; ch += 4) {
      uint32_t e = ch * 512u + (uint32_t)ln * 8u;   // bf16 elem in tile
      uint32_t row = e >> 5, col = e & 31u;
      gl2lds16(A + (size_t)(m0 + row) * 384u + k0 + col, lds_a + ch * 512);
      gl2lds16(B + (size_t)(n0 + row) * 384u + k0 + col, lds_b + ch * 512);
    }
    __syncthreads();
    const __bf16* pa = lds_a + (wr * 64 + c) * 32 + rq * 2;
    const __bf16* pb = lds_b + (wc * 64 + c) * 32 + rq * 2;
    v8bf af[4], bfr[4];
#pragma unroll
    for (int i = 0; i < 4; ++i) af[i]  = *(const v8bf*)(pa + i * 16 * 32);
#pragma unroll
    for (int i = 0; i < 4; ++i) bfr[i] = *(const v8bf*)(pb + i * 16 * 32);
#pragma unroll
    for (int mi = 0; mi < 4; ++mi)
#pragma unroll
      for (int ni = 0; ni < 4; ++ni)
        acc[mi][ni] = MFMA16(af[mi], bfr[ni], acc[mi][ni]);
    __syncthreads();
  }

  if (EPI == 0) {
    const uint32_t which = blockIdx.x / 3u;            // 1152 = 3 n-tiles per {q,k,v}
    __bf16* dst = (which == 0u) ? Qp : (which == 1u) ? Kp : Vp;
    const float scl = (which == 0u) ? 0.17677669529663687f : 1.0f;
#pragma unroll
    for (int ni = 0; ni < 4; ++ni) {
      uint32_t colg = n0 + wc * 64u + ni * 16u + c;
      float bv = biasv[colg];
      uint32_t cw = colg - which * 384u;
      uint32_t head = cw >> 5, d = cw & 31u;
#pragma unroll
      for (int mi = 0; mi < 4; ++mi)
#pragma unroll
        for (int r = 0; r < 4; ++r) {
          uint32_t mg = m0 + wr * 64u + mi * 16u + rq + r;
          uint32_t win = mg / 49u, tok = mg - win * 49u;
          float val = (acc[mi][ni][r] + bv) * scl;
          dst[((size_t)(win * 12u + head) * 49u + tok) * 32u + d] = (__bf16)val;
        }
    }
  } else {
#pragma unroll
    for (int ni = 0; ni < 4; ++ni) {
      uint32_t colg = n0 + wc * 64u + ni * 16u + c;
      float bv = biasv[colg];
#pragma unroll
      for (int mi = 0; mi < 4; ++mi)
#pragma unroll
        for (int r = 0; r < 4; ++r) {
          uint32_t mg = m0 + wr * 64u + mi * 16u + rq + r;
          uint32_t win = mg / 49u, tok = mg - win * 49u;
          uint32_t b = win >> 6, wy = (win >> 3) & 7u, wx = win & 7u;
          uint32_t ty = tok / 7u, tx = tok - ty * 7u;
          uint32_t y = wy * 7u + ty + 3u; if (y >= 56u) y -= 56u;
          uint32_t x = wx * 7u + tx + 3u; if (x >= 56u) x -= 56u;
          Op[(((size_t)b * 56u + y) * 56u + x) * 384u + colg] = acc[mi][ni][r] + bv;
        }
    }
  }
}

// ---------------- fused window attention: one wave per (window, head) ----------------
// computes S^T = K @ Q^T (16 MFMA), bias+mask inline, in-register softmax over keys
// (16 local + shfl_xor 16/32), P -> per-wave LDS, O^T = V^T @ P^T (16 MFMA).
__global__ __launch_bounds__(256) void attn_kernel(const __bf16* __restrict__ Q,
                                                   const __bf16* __restrict__ K,
                                                   const __bf16* __restrict__ V,
                                                   const float* __restrict__ rpb,
                                                   __bf16* __restrict__ Oa) {
  __shared__ __bf16 plds[4][64 * 72];                  // per-wave P [64][64] pad->72
  const int tid = threadIdx.x, wv = tid >> 6, ln = tid & 63;
  const int c = ln & 15, rq = (ln >> 4) * 4;
  const uint32_t gwh = blockIdx.x * 4u + wv;           // < 24576
  const uint32_t win = gwh / 12u, head = gwh - win * 12u;
  const uint32_t wy = (win >> 3) & 7u, wx = win & 7u;
  const __bf16* qb = Q + (size_t)gwh * 1568u;          // 49*32
  const __bf16* kb = K + (size_t)gwh * 1568u;
  const __bf16* vb = V + (size_t)gwh * 1568u;

  v8bf qf[4], kf[4];
#pragma unroll
  for (int t = 0; t < 4; ++t) {                        // rows t*16+c (overread -> slack)
    qf[t] = *(const v8bf*)(qb + (t * 16 + c) * 32 + rq * 2);
    kf[t] = *(const v8bf*)(kb + (t * 16 + c) * 32 + rq * 2);
  }
  v4f st[4][4] = {};                                   // S^T[jt][it]: row j(key), col i(query)
#pragma unroll
  for (int jt = 0; jt < 4; ++jt)
#pragma unroll
    for (int it = 0; it < 4; ++it)
      st[jt][it] = MFMA16(kf[jt], qf[it], st[jt][it]);

  // --- bias + shift-mask ---
  int iy[4], ix[4], icls[4];
#pragma unroll
  for (int it = 0; it < 4; ++it) {
    int ii = it * 16 + c; if (ii > 48) ii = 48;
    int y = ii / 7, x = ii - y * 7;
    iy[it] = y; ix[it] = x;
    int cy = (wy == 7u) ? ((y < 4) ? 1 : 2) : 0;
    int cx = (wx == 7u) ? ((x < 4) ? 1 : 2) : 0;
    icls[it] = cy * 3 + cx;
  }
#pragma unroll
  for (int jt = 0; jt < 4; ++jt)
#pragma unroll
    for (int r = 0; r < 4; ++r) {
      int j = jt * 16 + rq + r;
      int jc = j > 48 ? 48 : j;
      int jy = jc / 7, jx = jc - jy * 7;
      int cy = (wy == 7u) ? ((jy < 4) ? 1 : 2) : 0;
      int cx = (wx == 7u) ? ((jx < 4) ? 1 : 2) : 0;
      int jcls = cy * 3 + cx;
      bool jvalid = (j < 49);
#pragma unroll
      for (int it = 0; it < 4; ++it) {
        float s = st[jt][it][r];
        if (jvalid) {
          int idx = ((iy[it] - jy + 6) * 13 + (ix[it] - jx + 6)) * 12 + (int)head;
          s += rpb[idx] + ((icls[it] == jcls) ? 0.f : -100.f);
        } else s = -1e30f;
        st[jt][it][r] = s;
      }
    }

  // --- softmax over j, per column i ---
  float rinv[4];
#pragma unroll
  for (int it = 0; it < 4; ++it) {
    float m = -1e30f;
#pragma unroll
    for (int jt = 0; jt < 4; ++jt)
#pragma unroll
      for (int r = 0; r < 4; ++r) m = fmaxf(m, st[jt][it][r]);
    m = fmaxf(m, __shfl_xor(m, 16));
    m = fmaxf(m, __shfl_xor(m, 32));
    float sum = 0.f;
#pragma unroll
    for (int jt = 0; jt < 4; ++jt)
#pragma unroll
      for (int r = 0; r < 4; ++r) {
        float p = __expf(st[jt][it][r] - m);
        st[jt][it][r] = p; sum += p;
      }
    sum += __shfl_xor(sum, 16);
    sum += __shfl_xor(sum, 32);
    rinv[it] = 1.0f / sum;
  }

  // --- P -> LDS (row-major [i][j], pad 72) ---
  __bf16* pw = plds[wv];
#pragma unroll
  for (int jt = 0; jt < 4; ++jt)
#pragma unroll
    for (int it = 0; it < 4; ++it) {
      v4bf pk;
#pragma unroll
      for (int r = 0; r < 4; ++r) pk[r] = (__bf16)st[jt][it][r];
      *(v4bf*)(pw + (it * 16 + c) * 72 + jt * 16 + rq) = pk;
    }

  // --- O^T = V^T @ P^T ---
  v4f ot[2][4] = {};
#pragma unroll
  for (int ks2 = 0; ks2 < 2; ++ks2) {
    v8bf av[2];
#pragma unroll
    for (int m16 = 0; m16 < 2; ++m16)
#pragma unroll
      for (int jj = 0; jj < 8; ++jj)
        av[m16][jj] = vb[(ks2 * 32 + rq * 2 + jj) * 32 + m16 * 16 + c];
#pragma unroll
    for (int it = 0; it < 4; ++it) {
      v8bf pf = *(const v8bf*)(pw + (it * 16 + c) * 72 + ks2 * 32 + rq * 2);
#pragma unroll
      for (int m16 = 0; m16 < 2; ++m16)
        ot[m16][it] = MFMA16(av[m16], pf, ot[m16][it]);
    }
  }

  // --- store O: attnout[win*49+i][head*32+d] bf16 ---
#pragma unroll
  for (int it = 0; it < 4; ++it) {
    int i = it * 16 + c;
    if (i < 49) {
      float ri = rinv[it];
#pragma unroll
      for (int m16 = 0; m16 < 2; ++m16) {
        v4bf o;
#pragma unroll
        for (int r = 0; r < 4; ++r) o[r] = (__bf16)(ot[m16][it][r] * ri);
        *(v4bf*)(Oa + ((size_t)win * 49u + i) * 384u + head * 32u + m16 * 16 + rq) = o;
      }
    }
  }
}

// ---------------- launch ----------------
extern "C" void kernel_launch(void* const* d_in, const int* in_sizes, int n_in,
                              void* d_out, int out_size, void* d_ws, size_t ws_size,
                              hipStream_t stream) {
  const float* x      = (const float*)d_in[0];
  const float* qkv_w  = (const float*)d_in[1];
  const float* qkv_b  = (const float*)d_in[2];
  const float* proj_w = (const float*)d_in[3];
  const float* proj_b = (const float*)d_in[4];
  const float* rpb    = (const float*)d_in[5];
  float* out = (float*)d_out;

  char* w = (char*)d_ws;
  __bf16* Xw = (__bf16*)(w);                           // 77,070,336 B; later aliased as attnout
  __bf16* Wq = (__bf16*)(w + 77070336);                // 884,736 B
  __bf16* Wp = (__bf16*)(w + 77955072);                // 294,912 B
  __bf16* Qb = (__bf16*)(w + 78250240);                // 77,070,336 + 4K slack each
  __bf16* Kb = (__bf16*)(w + 78250240 + 77074432);
  __bf16* Vb = (__bf16*)(w + 78250240 + 154148864);    // total ws use ~295 MiB

  gather_cvt_x<<<37632, 256, 0, stream>>>(x, Xw);
  cvt_w_kernel<<<576, 256, 0, stream>>>(qkv_w, proj_w, Wq, Wp);
  gemm_bt<0><<<dim3(9, 784), 256, 0, stream>>>(Xw, Wq, qkv_b, Qb, Kb, Vb, nullptr);
  attn_kernel<<<6144, 256, 0, stream>>>(Qb, Kb, Vb, rpb, Xw /*attnout*/);
  gemm_bt<1><<<dim3(3, 784), 256, 0, stream>>>(Xw, Wp, proj_b, nullptr, nullptr, nullptr, out);
}